// Round 7
// baseline (419.425 us; speedup 1.0000x reference)
//
#include <hip/hip_runtime.h>
#include <math.h>

#define BB 4
#define CC 256
#define HH 64
#define WW 64
#define KP 9
#define GG 32
#define HWW (HH*WW)                 // 4096
#define FEL ((size_t)BB*CC*HH*WW)   // 4194304
#define GN_CNT 32768.0f             // (CC/GG)*H*W

typedef __bf16 bf16x8 __attribute__((ext_vector_type(8)));
typedef float  f32x4  __attribute__((ext_vector_type(4)));

__device__ __forceinline__ float bflo(unsigned u) {
    union { unsigned u; float f; } x; x.u = u << 16; return x.f;
}
__device__ __forceinline__ float bfhi(unsigned u) {
    union { unsigned u; float f; } x; x.u = u & 0xffff0000u; return x.f;
}

// XOR-swizzled LDS addressing, 256-element (512 B) rows:
#define VT256_RD(row, P)  (((row) << 8) + ((((P) ^ ((row) & 7))) << 3))
#define VT256_WR(row, u)  (((row) << 8) + (((((u) >> 1) ^ ((row) & 7))) << 3) + (((u) & 1) << 2))
// 128-element (256 B) rows (deform half-channel buffers), P = 8-elem chunk 0..15:
#define VT128_RD(row, P)  (((row) << 7) + ((((P) ^ ((row) & 7))) << 3))

// ---------------------------------------------------------------------------
// All weight prep + stats zeroing, one kernel.
// frag layout [9][c0:8][o16][lane:64][j:8]; lane l holds W[o16*16+(l&15)][c0*32+(l>>4)*8+j]
__global__ void prep_all(const float* __restrict__ w1, const float* __restrict__ wc,
                         const float* __restrict__ wr, const float* __restrict__ w18,
                         __bf16* __restrict__ f1, __bf16* __restrict__ fc,
                         __bf16* __restrict__ fr, __bf16* __restrict__ f18,
                         float* __restrict__ stats) {
    int gid = blockIdx.x * 256 + threadIdx.x;
    if (gid < 768) stats[gid] = 0.f;
    const int NW = 589824;
    if (gid < 3 * NW) {
        int which = gid / NW;
        int idx = gid - which * NW;
        int j   = idx & 7;
        int l   = (idx >> 3) & 63;
        int o16 = (idx >> 9) & 15;
        int c0  = (idx >> 13) & 7;
        int k   = idx >> 16;
        int o = o16 * 16 + (l & 15);
        int c = c0 * 32 + (l >> 4) * 8 + j;
        const float* src = (which == 0) ? w1 : ((which == 1) ? wc : wr);
        __bf16* dst = (which == 0) ? f1 : ((which == 1) ? fc : fr);
        dst[idx] = (__bf16)src[(size_t)(o * 256 + c) * 9 + k];
    } else {
        int idx = gid - 3 * NW;   // < 73728
        int j   = idx & 7;
        int l   = (idx >> 3) & 63;
        int o16 = (idx >> 9) & 1;
        int c0  = (idx >> 10) & 7;
        int k   = idx >> 13;
        int o = o16 * 16 + (l & 15);
        int c = c0 * 32 + (l >> 4) * 8 + j;
        float v = (o < 18) ? w18[(size_t)(o * 256 + c) * 9 + k] : 0.f;
        f18[idx] = (__bf16)v;
    }
}

// ---------------------------------------------------------------------------
// NCHW fp32 -> NHWC bf16 for both feature maps.
__global__ void transpose_feat(const float* __restrict__ cls,
                               const float* __restrict__ reg,
                               __bf16* __restrict__ out_cls,
                               __bf16* __restrict__ out_reg) {
    __shared__ float tile[64][65];
    int c0 = blockIdx.x * 64;
    int y  = blockIdx.y;
    int b  = blockIdx.z & 3;
    const float* in = (blockIdx.z >> 2) ? reg : cls;
    __bf16* out     = (blockIdx.z >> 2) ? out_reg : out_cls;
    int lx = threadIdx.x & 63;
    int q  = threadIdx.x >> 6;
    for (int j = 0; j < 16; ++j) {
        int ci = q * 16 + j;
        tile[ci][lx] = in[(((size_t)b*CC + c0 + ci)*HH + y)*WW + lx];
    }
    __syncthreads();
    for (int j = 0; j < 16; ++j) {
        int xi = q * 16 + j;
        out[(((size_t)b*HH + y)*WW + xi)*CC + c0 + lx] = (__bf16)tile[lx][xi];
    }
}

// ---------------------------------------------------------------------------
// conv3x3 C256->C256 via bf16 MFMA. o-quarter split: grid 1024, blk&3=b,
// (blk>>2)&3=oq, y=blk>>4. 4 blocks/CU.
__global__ __launch_bounds__(256, 4) void conv1_mfma(
    const __bf16* __restrict__ in_cl,   // [B,H,W,256] bf16
    const __bf16* __restrict__ wf,      // frag [9][8][16][64][8]
    const float* __restrict__ bias,
    __bf16* __restrict__ t_out,         // [B,H,W,256] bf16 (pre-GN)
    float* __restrict__ stats)
{
    __shared__ __bf16 Vt[66 * 256];
    __shared__ float groupStats[64];
    int blk = blockIdx.x;
    int bb = blk & 3;
    int oq = (blk >> 2) & 3;
    int y  = blk >> 4;
    int t  = threadIdx.x;
    int w  = t >> 6;
    int l  = t & 63;
    int quad = l >> 4;
    int l15  = l & 15;
    if (t < 64) groupStats[t] = 0.f;

    const __bf16* inb = in_cl + (size_t)bb * HWW * CC;
    f32x4 acc[4];
    #pragma unroll
    for (int i = 0; i < 4; ++i) acc[i] = (f32x4){0.f, 0.f, 0.f, 0.f};

    for (int ky = 0; ky < 3; ++ky) {
        int yy = y + ky - 1;
        bool yok = (yy >= 0 && yy < HH);
        __syncthreads();
        for (int u = t; u < 66 * 64; u += 256) {
            int xl = u >> 6, cu = u & 63;
            int gx = xl - 1;
            uint2 val = make_uint2(0u, 0u);
            if (yok && gx >= 0 && gx < WW)
                val = *(const uint2*)(inb + ((size_t)(yy * WW + gx)) * CC + cu * 4);
            *(uint2*)&Vt[VT256_WR(xl, cu)] = val;
        }
        __syncthreads();
        #pragma unroll
        for (int kx = 0; kx < 3; ++kx) {
            int k = ky * 3 + kx;
            const bf16x8* wbase = (const bf16x8*)(wf + (size_t)k * 65536);
            for (int c0 = 0; c0 < 8; ++c0) {
                bf16x8 a[4];
                #pragma unroll
                for (int pt = 0; pt < 4; ++pt) {
                    int row = pt * 16 + l15 + kx;
                    a[pt] = *(const bf16x8*)&Vt[VT256_RD(row, c0 * 4 + quad)];
                }
                bf16x8 bfr = wbase[(c0 * 16 + (oq * 4 + w)) * 64 + l];
                #pragma unroll
                for (int pt = 0; pt < 4; ++pt)
                    acc[pt] = __builtin_amdgcn_mfma_f32_16x16x32_bf16(
                        a[pt], bfr, acc[pt], 0, 0, 0);
            }
        }
    }
    // D[m=px][n=o]; px = pt*16 + quad*4 + r; o = oq*64 + w*16 + l15
    {
        int o = oq * 64 + w * 16 + l15;
        float bi = bias[o];
        float s1 = 0.f, s2 = 0.f;
        #pragma unroll
        for (int pt = 0; pt < 4; ++pt)
            #pragma unroll
            for (int r = 0; r < 4; ++r) {
                float v = acc[pt][r] + bi;
                int px = pt * 16 + quad * 4 + r;
                t_out[(((size_t)bb * HH + y) * WW + px) * CC + o] = (__bf16)v;
                s1 += v; s2 += v * v;
            }
        s1 += __shfl_xor(s1, 16, 64); s1 += __shfl_xor(s1, 32, 64);
        s2 += __shfl_xor(s2, 16, 64); s2 += __shfl_xor(s2, 32, 64);
        if (quad == 0) {
            atomicAdd(&groupStats[(o >> 3) * 2],     s1);
            atomicAdd(&groupStats[(o >> 3) * 2 + 1], s2);
        }
    }
    __syncthreads();
    if (t < 64) atomicAdd(&stats[bb * 64 + t], groupStats[t]);
}

// ---------------------------------------------------------------------------
// Offset head conv3x3 C256->18 via bf16 MFMA with GN+ReLU fused into staging.
// Half-row split: grid 512, blk&3=b, (blk>>2)&1=xh, y=blk>>3.
__global__ __launch_bounds__(256, 4) void conv18_mfma(
    const __bf16* __restrict__ t_bf,    // [B,H,W,256] bf16 raw (pre-GN)
    const __bf16* __restrict__ wf18,    // frag [9][8][2][64][8]
    const float* __restrict__ bias,     // [18]
    const float* __restrict__ stats,    // conv1 GN stats, + b*64
    const float* __restrict__ gamma, const float* __restrict__ beta,
    float* __restrict__ pts)            // [B,18,H,W]
{
    __shared__ __bf16 Vt[34 * 256];
    int blk = blockIdx.x;
    int bb = blk & 3;
    int xh = (blk >> 2) & 1;
    int y  = blk >> 3;
    int t  = threadIdx.x;
    int w  = t >> 6;
    int l  = t & 63;
    int quad = l >> 4;
    int l15  = l & 15;
    int mt   = w & 1;
    int o16  = w >> 1;
    int x0   = xh * 32;
    const __bf16* inb = t_bf + (size_t)bb * HWW * CC;

    int cbase = (t & 63) * 4;
    int g = cbase >> 3;
    float mu = stats[bb * 64 + g * 2]     * (1.f / GN_CNT);
    float ms = stats[bb * 64 + g * 2 + 1] * (1.f / GN_CNT);
    float rs = rsqrtf(ms - mu * mu + 1e-5f);
    float sc[4], sh[4];
    #pragma unroll
    for (int j = 0; j < 4; ++j) {
        float ga = gamma[cbase + j];
        sc[j] = rs * ga;
        sh[j] = beta[cbase + j] - mu * rs * ga;
    }

    f32x4 acc = (f32x4){0.f, 0.f, 0.f, 0.f};

    for (int ky = 0; ky < 3; ++ky) {
        int yy = y + ky - 1;
        bool yok = (yy >= 0 && yy < HH);
        __syncthreads();
        for (int u = t; u < 34 * 64; u += 256) {
            int xl = u >> 6, cu = u & 63;
            int gx = x0 - 1 + xl;
            uint2 val = make_uint2(0u, 0u);
            if (yok && gx >= 0 && gx < WW) {
                uint2 q = *(const uint2*)(inb + ((size_t)(yy * WW + gx)) * CC + cu * 4);
                float v0 = fmaxf(bflo(q.x) * sc[0] + sh[0], 0.f);
                float v1 = fmaxf(bfhi(q.x) * sc[1] + sh[1], 0.f);
                float v2 = fmaxf(bflo(q.y) * sc[2] + sh[2], 0.f);
                float v3 = fmaxf(bfhi(q.y) * sc[3] + sh[3], 0.f);
                __bf16 o4[4] = {(__bf16)v0, (__bf16)v1, (__bf16)v2, (__bf16)v3};
                val = *(const uint2*)o4;
            }
            *(uint2*)&Vt[VT256_WR(xl, cu)] = val;
        }
        __syncthreads();
        #pragma unroll
        for (int kx = 0; kx < 3; ++kx) {
            int k = ky * 3 + kx;
            const bf16x8* wbase = (const bf16x8*)(wf18 + (size_t)k * 8192);
            for (int c0 = 0; c0 < 8; ++c0) {
                int row = mt * 16 + l15 + kx;
                bf16x8 a = *(const bf16x8*)&Vt[VT256_RD(row, c0 * 4 + quad)];
                bf16x8 bfr = wbase[(c0 * 2 + o16) * 64 + l];
                acc = __builtin_amdgcn_mfma_f32_16x16x32_bf16(a, bfr, acc, 0, 0, 0);
            }
        }
    }
    {
        int o = o16 * 16 + l15;
        if (o < 18) {
            float bi = bias[o];
            float4 st;
            st.x = acc[0] + bi;
            st.y = acc[1] + bi;
            st.z = acc[2] + bi;
            st.w = acc[3] + bi;
            *(float4*)(pts + (((size_t)bb*18 + o)*HH + y)*WW + x0 + mt*16 + quad*4) = st;
        }
    }
}

// ---------------------------------------------------------------------------
// Deformable conv via bf16 MFMA, 512-thread blocks (8 waves, 32 o each).
// Per stage s: [weight loads W(s-1)] -> [gather loads G(s), 16B/lane] ->
// sched_barrier -> [MFMA(s-1): waits only on W] -> sched_barrier ->
// [combine(s): waits on G] -> barrier. grid 512: blk&7=b*2+which, y=blk>>3.
__global__ __launch_bounds__(512, 4) void deform_mfma(
    const __bf16* __restrict__ cls_cl, const __bf16* __restrict__ reg_cl,
    const __bf16* __restrict__ wfc, const __bf16* __restrict__ wfr,
    const float* __restrict__ pts,
    __bf16* __restrict__ out_cls, __bf16* __restrict__ out_reg,
    float* __restrict__ stats)
{
    __shared__ float pairW4[576 * 4];    // 9216 B
    __shared__ int   pairO4[576 * 4];    // 9216 B
    __shared__ __bf16 Vt[2][64 * 128];   // 2 x 16 KB (c-half tiles)
    __shared__ float groupStats[64];

    int blk = blockIdx.x;
    int g8  = blk & 7;
    int which = g8 & 1;
    int bb  = g8 >> 1;
    int y   = blk >> 3;
    const __bf16* featb = (which ? reg_cl : cls_cl) + (size_t)bb * HWW * CC;
    const __bf16* wf    = which ? wfr : wfc;
    __bf16* outp  = which ? out_reg : out_cls;
    float* statsP = stats + 256 + which * 256 + bb * 64;

    int t = threadIdx.x;        // 0..511
    int w = t >> 6;             // 0..7
    int l = t & 63;
    int quad = l >> 4;
    int l15  = l & 15;
    int cq4  = t & 15;          // 8-channel chunk within 128-c half
    int pxg  = t >> 4;          // px sub-index 0..31

    if (t < 64) groupStats[t] = 0.f;
    // phase 0: bilinear weights + corner element offsets per (k, px)
    for (int j = t; j < 576; j += 512) {
        int k = j >> 6;
        int x = j & 63;
        float py  = pts[(((size_t)bb*18 + 2*k)*HH + y)*WW + x] + (float)y;
        float pxf = pts[(((size_t)bb*18 + 2*k + 1)*HH + y)*WW + x] + (float)x;
        float y0f = floorf(py), x0f = floorf(pxf);
        float wy = py - y0f, wx = pxf - x0f;
        int iy0 = (int)y0f, ix0 = (int)x0f;
        int iy1 = iy0 + 1,  ix1 = ix0 + 1;
        bool vy0 = (iy0 >= 0 && iy0 < HH), vy1 = (iy1 >= 0 && iy1 < HH);
        bool vx0 = (ix0 >= 0 && ix0 < WW), vx1 = (ix1 >= 0 && ix1 < WW);
        int cy0 = min(max(iy0, 0), HH-1), cy1 = min(max(iy1, 0), HH-1);
        int cx0 = min(max(ix0, 0), WW-1), cx1 = min(max(ix1, 0), WW-1);
        pairW4[j*4+0] = (1.f-wy)*(1.f-wx) * ((vy0 && vx0) ? 1.f : 0.f);
        pairW4[j*4+1] = (1.f-wy)*wx       * ((vy0 && vx1) ? 1.f : 0.f);
        pairW4[j*4+2] = wy*(1.f-wx)       * ((vy1 && vx0) ? 1.f : 0.f);
        pairW4[j*4+3] = wy*wx             * ((vy1 && vx1) ? 1.f : 0.f);
        pairO4[j*4+0] = (cy0*WW + cx0)*CC;
        pairO4[j*4+1] = (cy0*WW + cx1)*CC;
        pairO4[j*4+2] = (cy1*WW + cx0)*CC;
        pairO4[j*4+3] = (cy1*WW + cx1)*CC;
    }

    f32x4 acc[2][4];   // [ot][pt]
    #pragma unroll
    for (int i = 0; i < 2; ++i)
        #pragma unroll
        for (int j = 0; j < 4; ++j)
            acc[i][j] = (f32x4){0.f, 0.f, 0.f, 0.f};

    bf16x8 wreg[4][2];
    uint4  L[2][4];

    // issue gather loads for stage s (2 px-chunks x 4 corners, 16B each)
    auto gathers = [&](int s) {
        int k = s >> 1, ch = s & 1;
        const __bf16* fb = featb + ch * 128 + cq4 * 8;
        #pragma unroll
        for (int it = 0; it < 2; ++it) {
            int j = k * 64 + it * 32 + pxg;
            int4 ov = *(const int4*)&pairO4[j * 4];
            L[it][0] = *(const uint4*)(fb + ov.x);
            L[it][1] = *(const uint4*)(fb + ov.y);
            L[it][2] = *(const uint4*)(fb + ov.z);
            L[it][3] = *(const uint4*)(fb + ov.w);
        }
    };
    // issue weight loads for stage s
    auto wloads = [&](int s) {
        int k = s >> 1, ch = s & 1;
        const bf16x8* wbase = (const bf16x8*)(wf + (size_t)k * 65536);
        #pragma unroll
        for (int u = 0; u < 4; ++u)
            #pragma unroll
            for (int ot = 0; ot < 2; ++ot)
                wreg[u][ot] = wbase[(((ch * 4 + u) * 16) + (w * 2 + ot)) * 64 + l];
    };
    // MFMAs of stage s from buf[s&1] using wreg
    auto stage_mfma = [&](int s) {
        const __bf16* buf = &Vt[s & 1][0];
        #pragma unroll
        for (int u = 0; u < 4; ++u) {
            bf16x8 a[4];
            #pragma unroll
            for (int pt = 0; pt < 4; ++pt)
                a[pt] = *(const bf16x8*)&buf[VT128_RD(pt * 16 + l15, u * 4 + quad)];
            #pragma unroll
            for (int ot = 0; ot < 2; ++ot)
                #pragma unroll
                for (int pt = 0; pt < 4; ++pt)
                    acc[ot][pt] = __builtin_amdgcn_mfma_f32_16x16x32_bf16(
                        wreg[u][ot], a[pt], acc[ot][pt], 0, 0, 0);
        }
    };
    // bilinear combine + b128 write to buf[s&1]
    auto combine = [&](int s) {
        __bf16* buf = &Vt[s & 1][0];
        int k = s >> 1;
        #pragma unroll
        for (int it = 0; it < 2; ++it) {
            int pxi = it * 32 + pxg;
            int j = k * 64 + pxi;
            float4 wv = *(const float4*)&pairW4[j * 4];
            __bf16 o8[8];
            #pragma unroll
            for (int h = 0; h < 4; ++h) {
                unsigned q0 = ((const unsigned*)&L[it][0])[h];
                unsigned q1 = ((const unsigned*)&L[it][1])[h];
                unsigned q2 = ((const unsigned*)&L[it][2])[h];
                unsigned q3 = ((const unsigned*)&L[it][3])[h];
                float lo = wv.x*bflo(q0) + wv.y*bflo(q1) + wv.z*bflo(q2) + wv.w*bflo(q3);
                float hi = wv.x*bfhi(q0) + wv.y*bfhi(q1) + wv.z*bfhi(q2) + wv.w*bfhi(q3);
                o8[h*2]   = (__bf16)lo;
                o8[h*2+1] = (__bf16)hi;
            }
            *(uint4*)&buf[VT128_RD(pxi, cq4)] = *(const uint4*)o8;
        }
    };

    __syncthreads();
    gathers(0);
    combine(0);
    #pragma unroll 1
    for (int s = 1; s < 18; ++s) {
        __syncthreads();
        wloads(s - 1);           // 8 vmem, issued FIRST
        gathers(s);              // 8 vmem gathers behind them
        __builtin_amdgcn_sched_barrier(0);
        stage_mfma(s - 1);       // waits only on weight loads (vmcnt keeps gathers in flight)
        __builtin_amdgcn_sched_barrier(0);
        combine(s);              // drains gathers, writes LDS
    }
    __syncthreads();
    wloads(17);
    stage_mfma(17);

    // epilogue: D[m=o][n=px]; o = w*32 + ot*16 + quad*4 + r; px = pt*16 + l15
    #pragma unroll
    for (int ot = 0; ot < 2; ++ot)
        #pragma unroll
        for (int r = 0; r < 4; ++r) {
            int o = w * 32 + ot * 16 + quad * 4 + r;
            __bf16* orow = outp + ((size_t)(bb*CC + o))*HWW + y*WW + l15;
            float s1 = 0.f, s2 = 0.f;
            #pragma unroll
            for (int pt = 0; pt < 4; ++pt) {
                float v = acc[ot][pt][r];
                orow[pt * 16] = (__bf16)v;
                s1 += v; s2 += v * v;
            }
            s1 += __shfl_xor(s1, 1, 64); s1 += __shfl_xor(s1, 2, 64);
            s1 += __shfl_xor(s1, 4, 64); s1 += __shfl_xor(s1, 8, 64);
            s2 += __shfl_xor(s2, 1, 64); s2 += __shfl_xor(s2, 2, 64);
            s2 += __shfl_xor(s2, 4, 64); s2 += __shfl_xor(s2, 8, 64);
            if (l15 == 0) {
                atomicAdd(&groupStats[(o >> 3) * 2],     s1);
                atomicAdd(&groupStats[(o >> 3) * 2 + 1], s2);
            }
        }
    __syncthreads();
    if (t < 64) atomicAdd(&statsP[t], groupStats[t]);
}

// ---------------------------------------------------------------------------
// GN + ReLU on bf16 NCHW deform outputs -> fp32 final outputs. 8 elems/thread.
__global__ void gn_relu_nchw(const __bf16* __restrict__ in_cls, const __bf16* __restrict__ in_reg,
                             float* __restrict__ out_cls, float* __restrict__ out_reg,
                             const float* __restrict__ stats_base,
                             const float* __restrict__ gcls, const float* __restrict__ bcls,
                             const float* __restrict__ greg, const float* __restrict__ breg) {
    int which = blockIdx.y;
    const __bf16* in = which ? in_reg  : in_cls;
    float* out       = which ? out_reg : out_cls;
    const float* st  = stats_base + (which ? 512 : 256);
    const float* gg  = which ? greg : gcls;
    const float* be  = which ? breg : bcls;
    size_t e = ((size_t)blockIdx.x * 256 + threadIdx.x) * 8;
    int c = (int)((e >> 12) & 255);
    int b = (int)(e >> 20);
    int g = c >> 3;
    float mu = st[(b*32 + g)*2] * (1.f / GN_CNT);
    float ms = st[(b*32 + g)*2 + 1] * (1.f / GN_CNT);
    float rs = rsqrtf(ms - mu*mu + 1e-5f);
    float ga = gg[c], bb = be[c];
    uint4 q = *(const uint4*)(in + e);
    float v[8] = {bflo(q.x), bfhi(q.x), bflo(q.y), bfhi(q.y),
                  bflo(q.z), bfhi(q.z), bflo(q.w), bfhi(q.w)};
    float4 r0, r1;
    r0.x = fmaxf((v[0] - mu)*rs*ga + bb, 0.f);
    r0.y = fmaxf((v[1] - mu)*rs*ga + bb, 0.f);
    r0.z = fmaxf((v[2] - mu)*rs*ga + bb, 0.f);
    r0.w = fmaxf((v[3] - mu)*rs*ga + bb, 0.f);
    r1.x = fmaxf((v[4] - mu)*rs*ga + bb, 0.f);
    r1.y = fmaxf((v[5] - mu)*rs*ga + bb, 0.f);
    r1.z = fmaxf((v[6] - mu)*rs*ga + bb, 0.f);
    r1.w = fmaxf((v[7] - mu)*rs*ga + bb, 0.f);
    *(float4*)(out + e)     = r0;
    *(float4*)(out + e + 4) = r1;
}

// ---------------------------------------------------------------------------
extern "C" void kernel_launch(void* const* d_in, const int* in_sizes, int n_in,
                              void* d_out, int out_size, void* d_ws, size_t ws_size,
                              hipStream_t stream) {
    (void)in_sizes; (void)n_in; (void)out_size; (void)ws_size;
    const float* cls_feat = (const float*)d_in[0];
    const float* reg_feat = (const float*)d_in[1];
    const float* offc_w   = (const float*)d_in[2];
    const float* offc_b   = (const float*)d_in[3];
    const float* offc_g   = (const float*)d_in[4];
    const float* offc_bt  = (const float*)d_in[5];
    const float* offo_w   = (const float*)d_in[6];
    const float* offo_b   = (const float*)d_in[7];
    const float* clsdc_w  = (const float*)d_in[8];
    const float* cls_g    = (const float*)d_in[9];
    const float* cls_bt   = (const float*)d_in[10];
    const float* regdc_w  = (const float*)d_in[11];
    const float* reg_g    = (const float*)d_in[12];
    const float* reg_bt   = (const float*)d_in[13];
    float* out = (float*)d_out;

    char* ws = (char*)d_ws;
    __bf16* reg_cl = (__bf16*)ws;                        // 8 MB
    __bf16* cls_cl = (__bf16*)(ws + 8388608);            // 8 MB
    __bf16* t_bf   = (__bf16*)(ws + 16777216);           // 8 MB
    __bf16* dc_cls = (__bf16*)(ws + 25165824);           // 8 MB
    __bf16* dc_reg = (__bf16*)(ws + 33554432);           // 8 MB
    __bf16* wt1f   = (__bf16*)(ws + 41943040);           // 1.18 MB
    __bf16* wtcf   = (__bf16*)(ws + 41943040 + 1179648);
    __bf16* wtrf   = (__bf16*)(ws + 41943040 + 2359296);
    __bf16* wf18   = (__bf16*)(ws + 41943040 + 3538944); // 147 KB
    float*  stats  = (float*)(ws + 41943040 + 3686400);  // 768 floats

    float* pts     = out;                 // [4,18,64,64]
    float* out_cls = out + 294912;
    float* out_reg = out + 294912 + FEL;

    hipLaunchKernelGGL(prep_all, dim3(7200), dim3(256), 0, stream,
                       offc_w, clsdc_w, regdc_w, offo_w, wt1f, wtcf, wtrf, wf18, stats);
    hipLaunchKernelGGL(transpose_feat, dim3(4, 64, 8), dim3(256), 0, stream,
                       cls_feat, reg_feat, cls_cl, reg_cl);
    hipLaunchKernelGGL(conv1_mfma, dim3(1024), dim3(256), 0, stream,
                       reg_cl, wt1f, offc_b, t_bf, stats);
    hipLaunchKernelGGL(conv18_mfma, dim3(512), dim3(256), 0, stream,
                       t_bf, wf18, offo_b, stats, offc_g, offc_bt, pts);
    hipLaunchKernelGGL(deform_mfma, dim3(512), dim3(512), 0, stream,
                       cls_cl, reg_cl, wtcf, wtrf, pts, dc_cls, dc_reg, stats);
    hipLaunchKernelGGL(gn_relu_nchw, dim3(2048, 2), dim3(256), 0, stream,
                       dc_cls, dc_reg, out_cls, out_reg,
                       stats, cls_g, cls_bt, reg_g, reg_bt);
}

// Round 8
// 230.421 us; speedup vs baseline: 1.8203x; 1.8203x over previous
//
#include <hip/hip_runtime.h>
#include <math.h>

#define BB 4
#define CC 256
#define HH 64
#define WW 64
#define KP 9
#define GG 32
#define HWW (HH*WW)                 // 4096
#define FEL ((size_t)BB*CC*HH*WW)   // 4194304
#define GN_CNT 32768.0f             // (CC/GG)*H*W

typedef __bf16 bf16x8 __attribute__((ext_vector_type(8)));
typedef float  f32x4  __attribute__((ext_vector_type(4)));
typedef float  f32x2  __attribute__((ext_vector_type(2)));

__device__ __forceinline__ float bflo(unsigned u) {
    union { unsigned u; float f; } x; x.u = u << 16; return x.f;
}
__device__ __forceinline__ float bfhi(unsigned u) {
    union { unsigned u; float f; } x; x.u = u & 0xffff0000u; return x.f;
}
__device__ __forceinline__ f32x2 up2(unsigned u) {
    return (f32x2){bflo(u), bfhi(u)};
}

// XOR-swizzled LDS addressing, 256-element (512 B) rows; P = 16B chunk 0..31:
#define VT256_RD(row, P)  (((row) << 8) + ((((P) ^ ((row) & 7))) << 3))
// 128-element (256 B) rows (deform half-channel buffers), P = 16B chunk 0..15:
#define VT128_RD(row, P)  (((row) << 7) + ((((P) ^ ((row) & 7))) << 3))

// ---------------------------------------------------------------------------
// Fused: NCHW fp32 -> NHWC bf16 transpose (blocks 0..2047) + all weight-frag
// prep + stats zeroing (blocks 2048..9247).
// frag layout [9][c0:8][o16][lane:64][j:8]; lane l holds W[o16*16+(l&15)][c0*32+(l>>4)*8+j]
__global__ void prep_and_transpose(
    const float* __restrict__ cls, const float* __restrict__ reg,
    __bf16* __restrict__ out_cls, __bf16* __restrict__ out_reg,
    const float* __restrict__ w1, const float* __restrict__ wc,
    const float* __restrict__ wr, const float* __restrict__ w18,
    __bf16* __restrict__ f1, __bf16* __restrict__ fc,
    __bf16* __restrict__ fr, __bf16* __restrict__ f18,
    float* __restrict__ stats)
{
    int blk = blockIdx.x;
    if (blk < 2048) {
        __shared__ float tile[64][65];
        int c0 = (blk & 3) * 64;
        int y  = (blk >> 2) & 63;
        int z  = blk >> 8;
        int b  = z & 3;
        const float* in = (z >> 2) ? reg : cls;
        __bf16* out     = (z >> 2) ? out_reg : out_cls;
        int lx = threadIdx.x & 63;
        int q  = threadIdx.x >> 6;
        for (int j = 0; j < 16; ++j) {
            int ci = q * 16 + j;
            tile[ci][lx] = in[(((size_t)b*CC + c0 + ci)*HH + y)*WW + lx];
        }
        __syncthreads();
        for (int j = 0; j < 16; ++j) {
            int xi = q * 16 + j;
            out[(((size_t)b*HH + y)*WW + xi)*CC + c0 + lx] = (__bf16)tile[lx][xi];
        }
        return;
    }
    int gid = (blk - 2048) * 256 + threadIdx.x;
    if (gid < 768) stats[gid] = 0.f;
    const int NW = 589824;
    if (gid < 3 * NW) {
        int which = gid / NW;
        int idx = gid - which * NW;
        int j   = idx & 7;
        int l   = (idx >> 3) & 63;
        int o16 = (idx >> 9) & 15;
        int c0  = (idx >> 13) & 7;
        int k   = idx >> 16;
        int o = o16 * 16 + (l & 15);
        int c = c0 * 32 + (l >> 4) * 8 + j;
        const float* src = (which == 0) ? w1 : ((which == 1) ? wc : wr);
        __bf16* dst = (which == 0) ? f1 : ((which == 1) ? fc : fr);
        dst[idx] = (__bf16)src[(size_t)(o * 256 + c) * 9 + k];
    } else {
        int idx = gid - 3 * NW;   // < 73728
        int j   = idx & 7;
        int l   = (idx >> 3) & 63;
        int o16 = (idx >> 9) & 1;
        int c0  = (idx >> 10) & 7;
        int k   = idx >> 13;
        int o = o16 * 16 + (l & 15);
        int c = c0 * 32 + (l >> 4) * 8 + j;
        float v = (o < 18) ? w18[(size_t)(o * 256 + c) * 9 + k] : 0.f;
        f18[idx] = (__bf16)v;
    }
}

// ---------------------------------------------------------------------------
// conv3x3 C256->C256 via bf16 MFMA. o-quarter split: grid 1024, blk&3=b,
// (blk>>2)&3=oq, y=blk>>4. 4 blocks/CU. 16B staging.
__global__ __launch_bounds__(256, 4) void conv1_mfma(
    const __bf16* __restrict__ in_cl,   // [B,H,W,256] bf16
    const __bf16* __restrict__ wf,      // frag [9][8][16][64][8]
    const float* __restrict__ bias,
    __bf16* __restrict__ t_out,         // [B,H,W,256] bf16 (pre-GN)
    float* __restrict__ stats)
{
    __shared__ __bf16 Vt[66 * 256];
    __shared__ float groupStats[64];
    int blk = blockIdx.x;
    int bb = blk & 3;
    int oq = (blk >> 2) & 3;
    int y  = blk >> 4;
    int t  = threadIdx.x;
    int w  = t >> 6;
    int l  = t & 63;
    int quad = l >> 4;
    int l15  = l & 15;
    if (t < 64) groupStats[t] = 0.f;

    const __bf16* inb = in_cl + (size_t)bb * HWW * CC;
    f32x4 acc[4];
    #pragma unroll
    for (int i = 0; i < 4; ++i) acc[i] = (f32x4){0.f, 0.f, 0.f, 0.f};

    for (int ky = 0; ky < 3; ++ky) {
        int yy = y + ky - 1;
        bool yok = (yy >= 0 && yy < HH);
        __syncthreads();
        for (int u = t; u < 66 * 32; u += 256) {
            int xl = u >> 5, cu = u & 31;
            int gx = xl - 1;
            uint4 val = make_uint4(0u, 0u, 0u, 0u);
            if (yok && gx >= 0 && gx < WW)
                val = *(const uint4*)(inb + ((size_t)(yy * WW + gx)) * CC + cu * 8);
            *(uint4*)&Vt[VT256_RD(xl, cu)] = val;
        }
        __syncthreads();
        #pragma unroll
        for (int kx = 0; kx < 3; ++kx) {
            int k = ky * 3 + kx;
            const bf16x8* wbase = (const bf16x8*)(wf + (size_t)k * 65536);
            for (int c0 = 0; c0 < 8; ++c0) {
                bf16x8 a[4];
                #pragma unroll
                for (int pt = 0; pt < 4; ++pt) {
                    int row = pt * 16 + l15 + kx;
                    a[pt] = *(const bf16x8*)&Vt[VT256_RD(row, c0 * 4 + quad)];
                }
                bf16x8 bfr = wbase[(c0 * 16 + (oq * 4 + w)) * 64 + l];
                #pragma unroll
                for (int pt = 0; pt < 4; ++pt)
                    acc[pt] = __builtin_amdgcn_mfma_f32_16x16x32_bf16(
                        a[pt], bfr, acc[pt], 0, 0, 0);
            }
        }
    }
    // D[m=px][n=o]; px = pt*16 + quad*4 + r; o = oq*64 + w*16 + l15
    {
        int o = oq * 64 + w * 16 + l15;
        float bi = bias[o];
        float s1 = 0.f, s2 = 0.f;
        #pragma unroll
        for (int pt = 0; pt < 4; ++pt)
            #pragma unroll
            for (int r = 0; r < 4; ++r) {
                float v = acc[pt][r] + bi;
                int px = pt * 16 + quad * 4 + r;
                t_out[(((size_t)bb * HH + y) * WW + px) * CC + o] = (__bf16)v;
                s1 += v; s2 += v * v;
            }
        s1 += __shfl_xor(s1, 16, 64); s1 += __shfl_xor(s1, 32, 64);
        s2 += __shfl_xor(s2, 16, 64); s2 += __shfl_xor(s2, 32, 64);
        if (quad == 0) {
            atomicAdd(&groupStats[(o >> 3) * 2],     s1);
            atomicAdd(&groupStats[(o >> 3) * 2 + 1], s2);
        }
    }
    __syncthreads();
    if (t < 64) atomicAdd(&stats[bb * 64 + t], groupStats[t]);
}

// ---------------------------------------------------------------------------
// Offset head conv3x3 C256->18 via bf16 MFMA, GN+ReLU fused into 16B staging.
// Half-row split: grid 512, blk&3=b, (blk>>2)&1=xh, y=blk>>3.
__global__ __launch_bounds__(256, 4) void conv18_mfma(
    const __bf16* __restrict__ t_bf,    // [B,H,W,256] bf16 raw (pre-GN)
    const __bf16* __restrict__ wf18,    // frag [9][8][2][64][8]
    const float* __restrict__ bias,     // [18]
    const float* __restrict__ stats,    // conv1 GN stats, + b*64
    const float* __restrict__ gamma, const float* __restrict__ beta,
    float* __restrict__ pts)            // [B,18,H,W]
{
    __shared__ __bf16 Vt[34 * 256];
    int blk = blockIdx.x;
    int bb = blk & 3;
    int xh = (blk >> 2) & 1;
    int y  = blk >> 3;
    int t  = threadIdx.x;
    int w  = t >> 6;
    int l  = t & 63;
    int quad = l >> 4;
    int l15  = l & 15;
    int mt   = w & 1;
    int o16  = w >> 1;
    int x0   = xh * 32;
    const __bf16* inb = t_bf + (size_t)bb * HWW * CC;

    // per-thread GN params for the 8 channels this thread stages (cu = t&31)
    int cu = t & 31;
    int cbase = cu * 8;
    float mu = stats[bb * 64 + cu * 2]     * (1.f / GN_CNT);
    float ms = stats[bb * 64 + cu * 2 + 1] * (1.f / GN_CNT);
    float rs = rsqrtf(ms - mu * mu + 1e-5f);
    float sc[8], sh[8];
    #pragma unroll
    for (int j = 0; j < 8; ++j) {
        float ga = gamma[cbase + j];
        sc[j] = rs * ga;
        sh[j] = beta[cbase + j] - mu * rs * ga;
    }

    f32x4 acc = (f32x4){0.f, 0.f, 0.f, 0.f};

    for (int ky = 0; ky < 3; ++ky) {
        int yy = y + ky - 1;
        bool yok = (yy >= 0 && yy < HH);
        __syncthreads();
        for (int u = t; u < 34 * 32; u += 256) {
            int xl = u >> 5;
            int gx = x0 - 1 + xl;
            uint4 val = make_uint4(0u, 0u, 0u, 0u);
            if (yok && gx >= 0 && gx < WW) {
                uint4 q = *(const uint4*)(inb + ((size_t)(yy * WW + gx)) * CC + cu * 8);
                __bf16 o8[8];
                unsigned qq[4] = {q.x, q.y, q.z, q.w};
                #pragma unroll
                for (int h = 0; h < 4; ++h) {
                    float lo = fmaxf(bflo(qq[h]) * sc[h*2]   + sh[h*2],   0.f);
                    float hi = fmaxf(bfhi(qq[h]) * sc[h*2+1] + sh[h*2+1], 0.f);
                    o8[h*2]   = (__bf16)lo;
                    o8[h*2+1] = (__bf16)hi;
                }
                val = *(const uint4*)o8;
            }
            *(uint4*)&Vt[VT256_RD(xl, cu)] = val;
        }
        __syncthreads();
        #pragma unroll
        for (int kx = 0; kx < 3; ++kx) {
            int k = ky * 3 + kx;
            const bf16x8* wbase = (const bf16x8*)(wf18 + (size_t)k * 8192);
            for (int c0 = 0; c0 < 8; ++c0) {
                int row = mt * 16 + l15 + kx;
                bf16x8 a = *(const bf16x8*)&Vt[VT256_RD(row, c0 * 4 + quad)];
                bf16x8 bfr = wbase[(c0 * 2 + o16) * 64 + l];
                acc = __builtin_amdgcn_mfma_f32_16x16x32_bf16(a, bfr, acc, 0, 0, 0);
            }
        }
    }
    {
        int o = o16 * 16 + l15;
        if (o < 18) {
            float bi = bias[o];
            float4 st;
            st.x = acc[0] + bi;
            st.y = acc[1] + bi;
            st.z = acc[2] + bi;
            st.w = acc[3] + bi;
            *(float4*)(pts + (((size_t)bb*18 + o)*HH + y)*WW + x0 + mt*16 + quad*4) = st;
        }
    }
}

// ---------------------------------------------------------------------------
// Deformable conv via bf16 MFMA, 512-thread blocks (8 waves, 32 o each),
// R6 pipeline shape (compiler-scheduled) + 16B gathers + packed-f32 combine.
// grid 512: blk&7=b*2+which (XCD locality), y=blk>>3.
__global__ __launch_bounds__(512, 4) void deform_mfma(
    const __bf16* __restrict__ cls_cl, const __bf16* __restrict__ reg_cl,
    const __bf16* __restrict__ wfc, const __bf16* __restrict__ wfr,
    const float* __restrict__ pts,
    __bf16* __restrict__ out_cls, __bf16* __restrict__ out_reg,
    float* __restrict__ stats)
{
    __shared__ float pairW4[576 * 4];    // 9216 B
    __shared__ int   pairO4[576 * 4];    // 9216 B
    __shared__ __bf16 Vt[2][64 * 128];   // 2 x 16 KB (c-half tiles)
    __shared__ float groupStats[64];

    int blk = blockIdx.x;
    int g8  = blk & 7;
    int which = g8 & 1;
    int bb  = g8 >> 1;
    int y   = blk >> 3;
    const __bf16* featb = (which ? reg_cl : cls_cl) + (size_t)bb * HWW * CC;
    const __bf16* wf    = which ? wfr : wfc;
    __bf16* outp  = which ? out_reg : out_cls;
    float* statsP = stats + 256 + which * 256 + bb * 64;

    int t = threadIdx.x;        // 0..511
    int w = t >> 6;             // 0..7
    int l = t & 63;
    int quad = l >> 4;
    int l15  = l & 15;
    int cq4  = t & 15;          // 16B chunk within 256B half-row
    int pxg  = t >> 4;          // px sub-index 0..31

    if (t < 64) groupStats[t] = 0.f;
    // phase 0: bilinear weights + corner element offsets per (k, px)
    for (int j = t; j < 576; j += 512) {
        int k = j >> 6;
        int x = j & 63;
        float py  = pts[(((size_t)bb*18 + 2*k)*HH + y)*WW + x] + (float)y;
        float pxf = pts[(((size_t)bb*18 + 2*k + 1)*HH + y)*WW + x] + (float)x;
        float y0f = floorf(py), x0f = floorf(pxf);
        float wy = py - y0f, wx = pxf - x0f;
        int iy0 = (int)y0f, ix0 = (int)x0f;
        int iy1 = iy0 + 1,  ix1 = ix0 + 1;
        bool vy0 = (iy0 >= 0 && iy0 < HH), vy1 = (iy1 >= 0 && iy1 < HH);
        bool vx0 = (ix0 >= 0 && ix0 < WW), vx1 = (ix1 >= 0 && ix1 < WW);
        int cy0 = min(max(iy0, 0), HH-1), cy1 = min(max(iy1, 0), HH-1);
        int cx0 = min(max(ix0, 0), WW-1), cx1 = min(max(ix1, 0), WW-1);
        pairW4[j*4+0] = (1.f-wy)*(1.f-wx) * ((vy0 && vx0) ? 1.f : 0.f);
        pairW4[j*4+1] = (1.f-wy)*wx       * ((vy0 && vx1) ? 1.f : 0.f);
        pairW4[j*4+2] = wy*(1.f-wx)       * ((vy1 && vx0) ? 1.f : 0.f);
        pairW4[j*4+3] = wy*wx             * ((vy1 && vx1) ? 1.f : 0.f);
        pairO4[j*4+0] = (cy0*WW + cx0)*CC;
        pairO4[j*4+1] = (cy0*WW + cx1)*CC;
        pairO4[j*4+2] = (cy1*WW + cx0)*CC;
        pairO4[j*4+3] = (cy1*WW + cx1)*CC;
    }

    f32x4 acc[2][4];   // [ot][pt]
    #pragma unroll
    for (int i = 0; i < 2; ++i)
        #pragma unroll
        for (int j = 0; j < 4; ++j)
            acc[i][j] = (f32x4){0.f, 0.f, 0.f, 0.f};

    uint4 L[2][4];

    // issue gather loads for stage s (2 px-chunks x 4 corners, 16B each)
    auto gathers = [&](int s) {
        int k = s >> 1, ch = s & 1;
        const __bf16* fb = featb + ch * 128 + cq4 * 8;
        #pragma unroll
        for (int it = 0; it < 2; ++it) {
            int j = k * 64 + it * 32 + pxg;
            int4 ov = *(const int4*)&pairO4[j * 4];
            L[it][0] = *(const uint4*)(fb + ov.x);
            L[it][1] = *(const uint4*)(fb + ov.y);
            L[it][2] = *(const uint4*)(fb + ov.z);
            L[it][3] = *(const uint4*)(fb + ov.w);
        }
    };
    // packed bilinear combine + b128 write to buf[s&1]
    auto combine = [&](int s) {
        __bf16* buf = &Vt[s & 1][0];
        int k = s >> 1;
        #pragma unroll
        for (int it = 0; it < 2; ++it) {
            int pxi = it * 32 + pxg;
            float4 wv = *(const float4*)&pairW4[(k * 64 + pxi) * 4];
            __bf16 o8[8];
            unsigned q0[4] = {L[it][0].x, L[it][0].y, L[it][0].z, L[it][0].w};
            unsigned q1[4] = {L[it][1].x, L[it][1].y, L[it][1].z, L[it][1].w};
            unsigned q2[4] = {L[it][2].x, L[it][2].y, L[it][2].z, L[it][2].w};
            unsigned q3[4] = {L[it][3].x, L[it][3].y, L[it][3].z, L[it][3].w};
            #pragma unroll
            for (int h = 0; h < 4; ++h) {
                f32x2 r = wv.x * up2(q0[h]);
                r += wv.y * up2(q1[h]);
                r += wv.z * up2(q2[h]);
                r += wv.w * up2(q3[h]);
                o8[h*2]   = (__bf16)r.x;
                o8[h*2+1] = (__bf16)r.y;
            }
            *(uint4*)&buf[VT128_RD(pxi, cq4)] = *(const uint4*)o8;
        }
    };
    // MFMAs of stage s from buf[s&1], weights streamed from L2
    auto stage_mfma = [&](int s) {
        int ch = s & 1;
        const __bf16* buf = &Vt[s & 1][0];
        const bf16x8* wbase = (const bf16x8*)(wf + (size_t)(s >> 1) * 65536);
        #pragma unroll
        for (int u = 0; u < 4; ++u) {
            bf16x8 a[4], bfr[2];
            #pragma unroll
            for (int pt = 0; pt < 4; ++pt)
                a[pt] = *(const bf16x8*)&buf[VT128_RD(pt * 16 + l15, u * 4 + quad)];
            #pragma unroll
            for (int ot = 0; ot < 2; ++ot)
                bfr[ot] = wbase[(((ch * 4 + u) * 16) + (w * 2 + ot)) * 64 + l];
            #pragma unroll
            for (int ot = 0; ot < 2; ++ot)
                #pragma unroll
                for (int pt = 0; pt < 4; ++pt)
                    acc[ot][pt] = __builtin_amdgcn_mfma_f32_16x16x32_bf16(
                        bfr[ot], a[pt], acc[ot][pt], 0, 0, 0);
        }
    };

    __syncthreads();
    gathers(0);
    combine(0);
    #pragma unroll 1
    for (int s = 1; s < 18; ++s) {
        __syncthreads();
        gathers(s);
        stage_mfma(s - 1);
        combine(s);
    }
    __syncthreads();
    stage_mfma(17);

    // epilogue: D[m=o][n=px]; o = w*32 + ot*16 + quad*4 + r; px = pt*16 + l15
    #pragma unroll
    for (int ot = 0; ot < 2; ++ot) {
        float s1 = 0.f, s2 = 0.f;
        #pragma unroll
        for (int r = 0; r < 4; ++r) {
            int o = w * 32 + ot * 16 + quad * 4 + r;
            __bf16* orow = outp + ((size_t)(bb*CC + o))*HWW + y*WW + l15;
            #pragma unroll
            for (int pt = 0; pt < 4; ++pt) {
                float v = acc[ot][pt][r];
                orow[pt * 16] = (__bf16)v;
                s1 += v; s2 += v * v;
            }
        }
        // lanes 0..31 share group w*4+ot*2+0; lanes 32..63 share w*4+ot*2+1
        s1 += __shfl_xor(s1, 1, 64); s1 += __shfl_xor(s1, 2, 64);
        s1 += __shfl_xor(s1, 4, 64); s1 += __shfl_xor(s1, 8, 64);
        s1 += __shfl_xor(s1, 16, 64);
        s2 += __shfl_xor(s2, 1, 64); s2 += __shfl_xor(s2, 2, 64);
        s2 += __shfl_xor(s2, 4, 64); s2 += __shfl_xor(s2, 8, 64);
        s2 += __shfl_xor(s2, 16, 64);
        if ((l & 31) == 0) {
            int g = w * 4 + ot * 2 + (l >> 5);
            atomicAdd(&groupStats[g * 2],     s1);
            atomicAdd(&groupStats[g * 2 + 1], s2);
        }
    }
    __syncthreads();
    if (t < 64) atomicAdd(&statsP[t], groupStats[t]);
}

// ---------------------------------------------------------------------------
// GN + ReLU on bf16 NCHW deform outputs -> fp32 final outputs. 8 elems/thread.
__global__ void gn_relu_nchw(const __bf16* __restrict__ in_cls, const __bf16* __restrict__ in_reg,
                             float* __restrict__ out_cls, float* __restrict__ out_reg,
                             const float* __restrict__ stats_base,
                             const float* __restrict__ gcls, const float* __restrict__ bcls,
                             const float* __restrict__ greg, const float* __restrict__ breg) {
    int which = blockIdx.y;
    const __bf16* in = which ? in_reg  : in_cls;
    float* out       = which ? out_reg : out_cls;
    const float* st  = stats_base + (which ? 512 : 256);
    const float* gg  = which ? greg : gcls;
    const float* be  = which ? breg : bcls;
    size_t e = ((size_t)blockIdx.x * 256 + threadIdx.x) * 8;
    int c = (int)((e >> 12) & 255);
    int b = (int)(e >> 20);
    int g = c >> 3;
    float mu = st[(b*32 + g)*2] * (1.f / GN_CNT);
    float ms = st[(b*32 + g)*2 + 1] * (1.f / GN_CNT);
    float rs = rsqrtf(ms - mu*mu + 1e-5f);
    float ga = gg[c], bb = be[c];
    uint4 q = *(const uint4*)(in + e);
    float v[8] = {bflo(q.x), bfhi(q.x), bflo(q.y), bfhi(q.y),
                  bflo(q.z), bfhi(q.z), bflo(q.w), bfhi(q.w)};
    float4 r0, r1;
    r0.x = fmaxf((v[0] - mu)*rs*ga + bb, 0.f);
    r0.y = fmaxf((v[1] - mu)*rs*ga + bb, 0.f);
    r0.z = fmaxf((v[2] - mu)*rs*ga + bb, 0.f);
    r0.w = fmaxf((v[3] - mu)*rs*ga + bb, 0.f);
    r1.x = fmaxf((v[4] - mu)*rs*ga + bb, 0.f);
    r1.y = fmaxf((v[5] - mu)*rs*ga + bb, 0.f);
    r1.z = fmaxf((v[6] - mu)*rs*ga + bb, 0.f);
    r1.w = fmaxf((v[7] - mu)*rs*ga + bb, 0.f);
    *(float4*)(out + e)     = r0;
    *(float4*)(out + e + 4) = r1;
}

// ---------------------------------------------------------------------------
extern "C" void kernel_launch(void* const* d_in, const int* in_sizes, int n_in,
                              void* d_out, int out_size, void* d_ws, size_t ws_size,
                              hipStream_t stream) {
    (void)in_sizes; (void)n_in; (void)out_size; (void)ws_size;
    const float* cls_feat = (const float*)d_in[0];
    const float* reg_feat = (const float*)d_in[1];
    const float* offc_w   = (const float*)d_in[2];
    const float* offc_b   = (const float*)d_in[3];
    const float* offc_g   = (const float*)d_in[4];
    const float* offc_bt  = (const float*)d_in[5];
    const float* offo_w   = (const float*)d_in[6];
    const float* offo_b   = (const float*)d_in[7];
    const float* clsdc_w  = (const float*)d_in[8];
    const float* cls_g    = (const float*)d_in[9];
    const float* cls_bt   = (const float*)d_in[10];
    const float* regdc_w  = (const float*)d_in[11];
    const float* reg_g    = (const float*)d_in[12];
    const float* reg_bt   = (const float*)d_in[13];
    float* out = (float*)d_out;

    char* ws = (char*)d_ws;
    __bf16* reg_cl = (__bf16*)ws;                        // 8 MB
    __bf16* cls_cl = (__bf16*)(ws + 8388608);            // 8 MB
    __bf16* t_bf   = (__bf16*)(ws + 16777216);           // 8 MB
    __bf16* dc_cls = (__bf16*)(ws + 25165824);           // 8 MB
    __bf16* dc_reg = (__bf16*)(ws + 33554432);           // 8 MB
    __bf16* wt1f   = (__bf16*)(ws + 41943040);           // 1.18 MB
    __bf16* wtcf   = (__bf16*)(ws + 41943040 + 1179648);
    __bf16* wtrf   = (__bf16*)(ws + 41943040 + 2359296);
    __bf16* wf18   = (__bf16*)(ws + 41943040 + 3538944); // 147 KB
    float*  stats  = (float*)(ws + 41943040 + 3686400);  // 768 floats

    float* pts     = out;                 // [4,18,64,64]
    float* out_cls = out + 294912;
    float* out_reg = out + 294912 + FEL;

    hipLaunchKernelGGL(prep_and_transpose, dim3(9248), dim3(256), 0, stream,
                       cls_feat, reg_feat, cls_cl, reg_cl,
                       offc_w, clsdc_w, regdc_w, offo_w,
                       wt1f, wtcf, wtrf, wf18, stats);
    hipLaunchKernelGGL(conv1_mfma, dim3(1024), dim3(256), 0, stream,
                       reg_cl, wt1f, offc_b, t_bf, stats);
    hipLaunchKernelGGL(conv18_mfma, dim3(512), dim3(256), 0, stream,
                       t_bf, wf18, offo_b, stats, offc_g, offc_bt, pts);
    hipLaunchKernelGGL(deform_mfma, dim3(512), dim3(512), 0, stream,
                       cls_cl, reg_cl, wtcf, wtrf, pts, dc_cls, dc_reg, stats);
    hipLaunchKernelGGL(gn_relu_nchw, dim3(2048, 2), dim3(256), 0, stream,
                       dc_cls, dc_reg, out_cls, out_reg,
                       stats, cls_g, cls_bt, reg_g, reg_bt);
}